// Round 9
// baseline (78.062 us; speedup 1.0000x reference)
//
#include <hip/hip_runtime.h>
#include <math.h>

// N=4194304 tokens, D=8, H=16, E=2
#define BLOCKS  16384              // 256 tokens per block, one shot, no loop
#define THREADS 256

typedef __attribute__((ext_vector_type(8))) short bf16x8;  // 8 bf16 (4 VGPRs)
typedef __attribute__((ext_vector_type(4))) float f32x4;
typedef __attribute__((ext_vector_type(2))) int   iv2;

union BF8 { unsigned u[4]; bf16x8 v; };

// permlane32 semantics (R4-R8 verified): swap32(a,a): x = a_lo||a_lo broadcast
// pattern -> used only for the gate cross-half sum here.
__device__ __forceinline__ iv2 swap32(int a, int b)
{ return __builtin_amdgcn_permlane32_swap(a, b, false, false); }

// Single-instruction packed f32->bf16 (RNE)
__device__ __forceinline__ unsigned cvt_pk_bf16(float lo, float hi)
{
    unsigned r;
    asm("v_cvt_pk_bf16_f32 %0, %1, %2" : "=v"(r) : "v"(lo), "v"(hi));
    return r;
}

// gelu(x) ~= x * sigmoid(1.702 x); validated R5-R8 (absmax 0.0 vs harness).
__device__ __forceinline__ float gelu_fast(float x)
{
    const float e = __expf(-1.702f * x);
    return x * __builtin_amdgcn_rcpf(1.0f + e);
}

// ---------------------------------------------------------------------------
// Prep (unchanged since R3): fold Wb/bb into gate + expert layers; collapse
// expert layer 2 (output summed over d).
//   wsc[0:16)    wg16[f]   = sum_d Wb[f][d] * (Wg[d][1]-Wg[d][0])
//   wsc[16]      cg ; wsc[17] sb2_0 ; wsc[18] sb2_1
//   wsc[32:64)   cb_e[h] ; wsc[64:96) s2_e[h]
//   wsc[128:640) M_e[f][h] = sum_d Wb[f][d]*We1[e][d][h] (M0 @128, M1 @384)
// ---------------------------------------------------------------------------
__global__ void moe_prep(const float* __restrict__ Wb,  const float* __restrict__ bb,
                         const float* __restrict__ Wg,  const float* __restrict__ bg,
                         const float* __restrict__ We1, const float* __restrict__ be1,
                         const float* __restrict__ We2, const float* __restrict__ be2,
                         float* __restrict__ wsc)
{
    const int t = threadIdx.x;
    if (t < 16) {
        float s = 0.f;
        #pragma unroll
        for (int d = 0; d < 8; ++d)
            s += Wb[t * 8 + d] * (Wg[d * 2 + 1] - Wg[d * 2 + 0]);
        wsc[t] = s;
    }
    if (t == 16) {
        float s = bg[1] - bg[0];
        #pragma unroll
        for (int d = 0; d < 8; ++d) s += bb[d] * (Wg[d * 2 + 1] - Wg[d * 2 + 0]);
        wsc[16] = s;
    }
    if (t == 17 || t == 18) {
        const int e = t - 17;
        float s = 0.f;
        #pragma unroll
        for (int d = 0; d < 8; ++d) s += be2[e * 8 + d];
        wsc[t] = s;
    }
    if (t >= 32 && t < 64) {
        const int e = (t - 32) >> 4, h = t & 15;
        float s = be1[e * 16 + h];
        #pragma unroll
        for (int d = 0; d < 8; ++d) s += bb[d] * We1[e * 128 + d * 16 + h];
        wsc[t] = s;
    }
    if (t >= 64 && t < 96) {
        const int e = (t - 64) >> 4, h = t & 15;
        float s = 0.f;
        #pragma unroll
        for (int d = 0; d < 8; ++d) s += We2[(e * 16 + h) * 8 + d];
        wsc[t] = s;
    }
    if (t >= 128 && t < 640) {
        const int idx = t - 128;
        const int e = idx >> 8, f = (idx >> 4) & 15, h = idx & 15;
        float s = 0.f;
        #pragma unroll
        for (int d = 0; d < 8; ++d) s += Wb[f * 8 + d] * We1[e * 128 + d * 16 + h];
        wsc[128 + idx] = s;
    }
}

// ---------------------------------------------------------------------------
// Main: STRAIGHTLINE — each wave handles exactly 64 tokens, no token loop.
// Structure is R7's verified 16x16x32 path (bpermute marshalling on the LDS
// pipe, VALU kept lean). With no loop, per-iteration invariant
// rematerialization cannot occur: the fragment preamble runs exactly once
// per 64 tokens.
// ---------------------------------------------------------------------------
__global__ void __launch_bounds__(THREADS, 4)
moe_main(const float* __restrict__ inp,
         const float* __restrict__ Wa, const float* __restrict__ ba,
         const float* __restrict__ wsc,
         float* __restrict__ blocksums)
{
    __shared__ float wavered[4];
    const int t  = threadIdx.x;
    const int l  = t & 63;
    const int lg = l >> 4;
    const int lr = l & 15;
    const bool lo16 = (l < 16);
    const bool lo32 = (l < 32);

    // ---- A fragments (zero-padded k annihilates B-side garbage) ----
    BF8 aWa, aM0, aM1;
    #pragma unroll
    for (int j2 = 0; j2 < 4; ++j2) {
        const float w0 = lo16 ? Wa[(2 * j2) * 16 + lr]     : 0.f;
        const float w1 = lo16 ? Wa[(2 * j2 + 1) * 16 + lr] : 0.f;
        aWa.u[j2] = cvt_pk_bf16(w0, w1);
        const int f0 = 8 * lg + 2 * j2;
        const float m00 = lo32 ? wsc[128 + f0 * 16 + lr]       : 0.f;
        const float m01 = lo32 ? wsc[128 + (f0 + 1) * 16 + lr] : 0.f;
        aM0.u[j2] = cvt_pk_bf16(m00, m01);
        const float m10 = lo32 ? wsc[384 + f0 * 16 + lr]       : 0.f;
        const float m11 = lo32 ? wsc[384 + (f0 + 1) * 16 + lr] : 0.f;
        aM1.u[j2] = cvt_pk_bf16(m10, m11);
    }

    // ---- C-in / epilogue vectors (C row = lg*4 + r) ----
    f32x4 cba, ccb0, ccb1, vwg, vs20, vs21;
    #pragma unroll
    for (int r = 0; r < 4; ++r) {
        const int h = lg * 4 + r;
        cba[r]  = ba[h];
        vwg[r]  = wsc[h];
        ccb0[r] = wsc[32 + h];
        ccb1[r] = wsc[48 + h];
        vs20[r] = wsc[64 + h];
        vs21[r] = wsc[80 + h];
    }
    const float cg4  = wsc[16] * 0.25f;   // 4 lane-groups each contribute once
    const float sbq0 = wsc[17] * 0.25f;   // 4 lanes per token add the bias
    const float sbq1 = wsc[18] * 0.25f;

    // ---- this wave's 64 tokens ----
    const int gwave = (blockIdx.x * THREADS + t) >> 6;
    const int tok   = gwave * 64 + l;
    const float4* __restrict__ p4 = (const float4*)inp;
    const float4 c0 = p4[2 * tok];
    const float4 c1 = p4[2 * tok + 1];

    unsigned pin[4];
    pin[0] = cvt_pk_bf16(c0.x, c0.y);
    pin[1] = cvt_pk_bf16(c0.z, c0.w);
    pin[2] = cvt_pk_bf16(c1.x, c1.y);
    pin[3] = cvt_pk_bf16(c1.z, c1.w);

    float local = 0.f;

    #pragma unroll
    for (int m = 0; m < 4; ++m) {
        // B-frag: tokens m*16..m*16+15 via bpermute (LDS pipe; garbage
        // k-blocks annihilated by aWa zeros)
        const int srcA = m * 64 + lr * 4;
        BF8 bin;
        #pragma unroll
        for (int j = 0; j < 4; ++j)
            bin.u[j] = (unsigned)__builtin_amdgcn_ds_bpermute(srcA, (int)pin[j]);

        const f32x4 C = __builtin_amdgcn_mfma_f32_16x16x32_bf16(
                            aWa.v, bin.v, cba, 0, 0, 0);
        f32x4 rh;
        #pragma unroll
        for (int r = 0; r < 4; ++r) rh[r] = fmaxf(C[r], 0.f);

        // gate: partial dot over this lane's 4 h-rows, +-32 via permlane
        // (VALU), +-16 via one shfl (LDS)
        float pg = cg4;
        #pragma unroll
        for (int r = 0; r < 4; ++r) pg = fmaf(rh[r], vwg[r], pg);
        const iv2 gs = swap32(__float_as_int(pg), __float_as_int(pg));
        float pg32 = __int_as_float(gs.x) + __int_as_float(gs.y);
        pg32 += __shfl_xor(pg32, 16);
        const bool sel = pg32 > 0.f;    // argmax tie -> expert 0

        // rh -> expert B-frag [K=16 features x N=16 tokens] via bpermute
        const unsigned pr0 = cvt_pk_bf16(rh[0], rh[1]);
        const unsigned pr1 = cvt_pk_bf16(rh[2], rh[3]);
        BF8 b2;
        #pragma unroll
        for (int j = 0; j < 4; ++j) {
            const int addr = ((lg * 2 + (j >> 1)) * 16 + lr) * 4;
            b2.u[j] = (unsigned)__builtin_amdgcn_ds_bpermute(
                          addr, (int)((j & 1) ? pr1 : pr0));
        }

        const f32x4 C0 = __builtin_amdgcn_mfma_f32_16x16x32_bf16(
                             aM0.v, b2.v, ccb0, 0, 0, 0);
        const f32x4 C1 = __builtin_amdgcn_mfma_f32_16x16x32_bf16(
                             aM1.v, b2.v, ccb1, 0, 0, 0);

        #pragma unroll
        for (int r = 0; r < 4; ++r) {
            const float pre = sel ? C1[r] : C0[r];
            const float g   = gelu_fast(pre);
            const float s2  = sel ? vs21[r] : vs20[r];
            local = fmaf(g, s2, local);
        }
        local += sel ? sbq1 : sbq0;
    }

    // wave reduce + block reduce
    #pragma unroll
    for (int off = 32; off > 0; off >>= 1)
        local += __shfl_down(local, off);
    if ((t & 63) == 0) wavered[t >> 6] = local;
    __syncthreads();
    if (t == 0)
        blocksums[blockIdx.x] = wavered[0] + wavered[1] + wavered[2] + wavered[3];
}

__global__ void __launch_bounds__(256)
moe_reduce(const float* __restrict__ blocksums, float* __restrict__ out)
{
    __shared__ float wavered[4];
    float v = 0.f;
    for (int i = threadIdx.x; i < BLOCKS; i += 256) v += blocksums[i];
    #pragma unroll
    for (int off = 32; off > 0; off >>= 1)
        v += __shfl_down(v, off);
    if ((threadIdx.x & 63) == 0) wavered[threadIdx.x >> 6] = v;
    __syncthreads();
    if (threadIdx.x == 0)
        out[0] = wavered[0] + wavered[1] + wavered[2] + wavered[3];
}

extern "C" void kernel_launch(void* const* d_in, const int* in_sizes, int n_in,
                              void* d_out, int out_size, void* d_ws, size_t ws_size,
                              hipStream_t stream)
{
    const float* inp = (const float*)d_in[0];
    const float* Wa  = (const float*)d_in[1];
    const float* ba  = (const float*)d_in[2];
    const float* Wb  = (const float*)d_in[3];
    const float* bb  = (const float*)d_in[4];
    const float* Wg  = (const float*)d_in[5];
    const float* bg  = (const float*)d_in[6];
    const float* We1 = (const float*)d_in[7];
    const float* be1 = (const float*)d_in[8];
    const float* We2 = (const float*)d_in[9];
    const float* be2 = (const float*)d_in[10];

    float* wsc       = (float*)d_ws;        // 640 floats of folded weights
    float* blocksums = (float*)d_ws + 640;  // BLOCKS floats
    float* out       = (float*)d_out;

    hipLaunchKernelGGL(moe_prep, dim3(1), dim3(640), 0, stream,
                       Wb, bb, Wg, bg, We1, be1, We2, be2, wsc);
    hipLaunchKernelGGL(moe_main, dim3(BLOCKS), dim3(THREADS), 0, stream,
                       inp, Wa, ba, wsc, blocksums);
    hipLaunchKernelGGL(moe_reduce, dim3(1), dim3(256), 0, stream,
                       blocksums, out);
}

// Round 10
// 56.888 us; speedup vs baseline: 1.3722x; 1.3722x over previous
//
#include <hip/hip_runtime.h>
#include <math.h>

// N=4194304 tokens, D=8, H=16, E=2
#define BLOCKS  4096
#define THREADS 256
#define NWAVES  (BLOCKS * THREADS / 64)   // 16384 waves
#define STEP    (NWAVES * 64)             // 1048576 tokens per grid sweep

typedef __attribute__((ext_vector_type(8))) short bf16x8;  // 8 bf16 (4 VGPRs)
typedef __attribute__((ext_vector_type(4))) float f32x4;
typedef __attribute__((ext_vector_type(2))) int   iv2;

union BF8 { unsigned u[4]; bf16x8 v; };

// permlane semantics (R4-R8 verified on-device, absmax 0.0):
//   swap32(a,a).x/.y : 32-lane-half exchange
//   swap16(a,a)      : row(16-lane-group) pair exchange; with the swap32 sum
//                      first, x+y gives the full 4-group sum in every lane.
__device__ __forceinline__ iv2 swap32(int a, int b)
{ return __builtin_amdgcn_permlane32_swap(a, b, false, false); }
__device__ __forceinline__ iv2 swap16(int a, int b)
{ return __builtin_amdgcn_permlane16_swap(a, b, false, false); }

// Single-instruction packed f32->bf16 (RNE)
__device__ __forceinline__ unsigned cvt_pk_bf16(float lo, float hi)
{
    unsigned r;
    asm("v_cvt_pk_bf16_f32 %0, %1, %2" : "=v"(r) : "v"(lo), "v"(hi));
    return r;
}

// gelu(x) ~= x * sigmoid(1.702 x); validated R5-R9 (absmax 0.0 vs harness).
__device__ __forceinline__ float gelu_fast(float x)
{
    const float e = __expf(-1.702f * x);
    return x * __builtin_amdgcn_rcpf(1.0f + e);
}

// ---------------------------------------------------------------------------
// Prep (unchanged since R3): fold Wb/bb into gate + expert layers; collapse
// expert layer 2 (output summed over d).
//   wsc[0:16)    wg16[f]   = sum_d Wb[f][d] * (Wg[d][1]-Wg[d][0])
//   wsc[16]      cg ; wsc[17] sb2_0 ; wsc[18] sb2_1
//   wsc[32:64)   cb_e[h] ; wsc[64:96) s2_e[h]
//   wsc[128:640) M_e[f][h] = sum_d Wb[f][d]*We1[e][d][h] (M0 @128, M1 @384)
// ---------------------------------------------------------------------------
__global__ void moe_prep(const float* __restrict__ Wb,  const float* __restrict__ bb,
                         const float* __restrict__ Wg,  const float* __restrict__ bg,
                         const float* __restrict__ We1, const float* __restrict__ be1,
                         const float* __restrict__ We2, const float* __restrict__ be2,
                         float* __restrict__ wsc)
{
    const int t = threadIdx.x;
    if (t < 16) {
        float s = 0.f;
        #pragma unroll
        for (int d = 0; d < 8; ++d)
            s += Wb[t * 8 + d] * (Wg[d * 2 + 1] - Wg[d * 2 + 0]);
        wsc[t] = s;
    }
    if (t == 16) {
        float s = bg[1] - bg[0];
        #pragma unroll
        for (int d = 0; d < 8; ++d) s += bb[d] * (Wg[d * 2 + 1] - Wg[d * 2 + 0]);
        wsc[16] = s;
    }
    if (t == 17 || t == 18) {
        const int e = t - 17;
        float s = 0.f;
        #pragma unroll
        for (int d = 0; d < 8; ++d) s += be2[e * 8 + d];
        wsc[t] = s;
    }
    if (t >= 32 && t < 64) {
        const int e = (t - 32) >> 4, h = t & 15;
        float s = be1[e * 16 + h];
        #pragma unroll
        for (int d = 0; d < 8; ++d) s += bb[d] * We1[e * 128 + d * 16 + h];
        wsc[t] = s;
    }
    if (t >= 64 && t < 96) {
        const int e = (t - 64) >> 4, h = t & 15;
        float s = 0.f;
        #pragma unroll
        for (int d = 0; d < 8; ++d) s += We2[(e * 16 + h) * 8 + d];
        wsc[t] = s;
    }
    if (t >= 128 && t < 640) {
        const int idx = t - 128;
        const int e = idx >> 8, f = (idx >> 4) & 15, h = idx & 15;
        float s = 0.f;
        #pragma unroll
        for (int d = 0; d < 8; ++d) s += Wb[f * 8 + d] * We1[e * 128 + d * 16 + h];
        wsc[128 + idx] = s;
    }
}

// ---------------------------------------------------------------------------
// Main: R7 grid/loop, but the inner 64-token body is PHASE-BATCHED so all
// same-kind ops are independent and their latencies overlap:
//   P1 all 16 layer-A bpermutes -> P2 4 MFMAs -> P3 rh+gates (all VALU,
//   swap32/swap16 butterfly, no LDS) -> P4 all 16 expert bpermutes ->
//   P5 8 MFMAs + epilogue.
// ---------------------------------------------------------------------------
__global__ void __launch_bounds__(THREADS, 4)
moe_main(const float* __restrict__ inp,
         const float* __restrict__ Wa, const float* __restrict__ ba,
         const float* __restrict__ wsc,
         float* __restrict__ blocksums, int ntok)
{
    __shared__ float wavered[4];
    const int t  = threadIdx.x;
    const int l  = t & 63;
    const int lg = l >> 4;
    const int lr = l & 15;
    const bool lo16 = (l < 16);
    const bool lo32 = (l < 32);

    // ---- static A fragments (zero-padded k annihilates B-side garbage) ----
    BF8 aWa, aM0, aM1;
    #pragma unroll
    for (int j2 = 0; j2 < 4; ++j2) {
        const float w0 = lo16 ? Wa[(2 * j2) * 16 + lr]     : 0.f;
        const float w1 = lo16 ? Wa[(2 * j2 + 1) * 16 + lr] : 0.f;
        aWa.u[j2] = cvt_pk_bf16(w0, w1);
        const int f0 = 8 * lg + 2 * j2;
        const float m00 = lo32 ? wsc[128 + f0 * 16 + lr]       : 0.f;
        const float m01 = lo32 ? wsc[128 + (f0 + 1) * 16 + lr] : 0.f;
        aM0.u[j2] = cvt_pk_bf16(m00, m01);
        const float m10 = lo32 ? wsc[384 + f0 * 16 + lr]       : 0.f;
        const float m11 = lo32 ? wsc[384 + (f0 + 1) * 16 + lr] : 0.f;
        aM1.u[j2] = cvt_pk_bf16(m10, m11);
    }

    // ---- static C-in / epilogue vectors (C row = lg*4 + r) ----
    f32x4 cba, ccb0, ccb1, vwg, vs20, vs21;
    #pragma unroll
    for (int r = 0; r < 4; ++r) {
        const int h = lg * 4 + r;
        cba[r]  = ba[h];
        vwg[r]  = wsc[h];
        ccb0[r] = wsc[32 + h];
        ccb1[r] = wsc[48 + h];
        vs20[r] = wsc[64 + h];
        vs21[r] = wsc[80 + h];
    }
    const float cg4  = wsc[16] * 0.25f;   // 4 lane-groups each contribute once
    const float sbq0 = wsc[17] * 0.25f;   // 4 lanes per token add the bias
    const float sbq1 = wsc[18] * 0.25f;

    const int gwave = (blockIdx.x * THREADS + t) >> 6;
    const float4* __restrict__ p4 = (const float4*)inp;
    float local = 0.f;

    // ntok = 4194304 = 4 * STEP exactly.
    const int niter = ntok / STEP;
    int tok = gwave * 64 + l;
    float4 a0 = p4[2 * tok];
    float4 a1 = p4[2 * tok + 1];

    for (int it = 0; it < niter; ++it) {
        const float4 c0 = a0;
        const float4 c1 = a1;
        if (it + 1 < niter) {              // prefetch next sweep's token
            a0 = p4[2 * (tok + STEP)];
            a1 = p4[2 * (tok + STEP) + 1];
        }
        tok += STEP;

        unsigned pin[4];
        pin[0] = cvt_pk_bf16(c0.x, c0.y);
        pin[1] = cvt_pk_bf16(c0.z, c0.w);
        pin[2] = cvt_pk_bf16(c1.x, c1.y);
        pin[3] = cvt_pk_bf16(c1.z, c1.w);

        // ---- P1: ALL layer-A B-frags (16 independent bpermutes) ----
        BF8 bin[4];
        #pragma unroll
        for (int m = 0; m < 4; ++m) {
            const int srcA = m * 64 + lr * 4;
            #pragma unroll
            for (int j = 0; j < 4; ++j)
                bin[m].u[j] = (unsigned)__builtin_amdgcn_ds_bpermute(
                                  srcA, (int)pin[j]);
        }

        // ---- P2: 4 independent layer-A MFMAs ----
        f32x4 Cm[4];
        #pragma unroll
        for (int m = 0; m < 4; ++m)
            Cm[m] = __builtin_amdgcn_mfma_f32_16x16x32_bf16(
                        aWa.v, bin[m].v, cba, 0, 0, 0);

        // ---- P3: relu + gate (pure VALU: swap32 + swap16 butterfly) ----
        f32x4 rh[4];
        bool  sel[4];
        #pragma unroll
        for (int m = 0; m < 4; ++m) {
            #pragma unroll
            for (int r = 0; r < 4; ++r) rh[m][r] = fmaxf(Cm[m][r], 0.f);
            float pg = cg4;
            #pragma unroll
            for (int r = 0; r < 4; ++r) pg = fmaf(rh[m][r], vwg[r], pg);
            const iv2 g32 = swap32(__float_as_int(pg), __float_as_int(pg));
            const float pgA = __int_as_float(g32.x) + __int_as_float(g32.y);
            const iv2 g16 = swap16(__float_as_int(pgA), __float_as_int(pgA));
            const float ptot = __int_as_float(g16.x) + __int_as_float(g16.y);
            sel[m] = ptot > 0.f;            // argmax tie -> expert 0
        }

        // ---- P4: ALL expert B-frags (16 independent bpermutes) ----
        BF8 b2[4];
        #pragma unroll
        for (int m = 0; m < 4; ++m) {
            const unsigned pr0 = cvt_pk_bf16(rh[m][0], rh[m][1]);
            const unsigned pr1 = cvt_pk_bf16(rh[m][2], rh[m][3]);
            #pragma unroll
            for (int j = 0; j < 4; ++j) {
                const int addr = ((lg * 2 + (j >> 1)) * 16 + lr) * 4;
                b2[m].u[j] = (unsigned)__builtin_amdgcn_ds_bpermute(
                                 addr, (int)((j & 1) ? pr1 : pr0));
            }
        }

        // ---- P5: expert MFMAs + epilogue (m+1's MFMAs hoistable over m's
        //      epilogue by the scheduler — all independent) ----
        #pragma unroll
        for (int m = 0; m < 4; ++m) {
            const f32x4 C0 = __builtin_amdgcn_mfma_f32_16x16x32_bf16(
                                 aM0.v, b2[m].v, ccb0, 0, 0, 0);
            const f32x4 C1 = __builtin_amdgcn_mfma_f32_16x16x32_bf16(
                                 aM1.v, b2[m].v, ccb1, 0, 0, 0);
            #pragma unroll
            for (int r = 0; r < 4; ++r) {
                const float pre = sel[m] ? C1[r] : C0[r];
                const float g   = gelu_fast(pre);
                const float s2  = sel[m] ? vs21[r] : vs20[r];
                local = fmaf(g, s2, local);
            }
            local += sel[m] ? sbq1 : sbq0;
        }
    }

    // wave reduce + block reduce
    #pragma unroll
    for (int off = 32; off > 0; off >>= 1)
        local += __shfl_down(local, off);
    if ((t & 63) == 0) wavered[t >> 6] = local;
    __syncthreads();
    if (t == 0)
        blocksums[blockIdx.x] = wavered[0] + wavered[1] + wavered[2] + wavered[3];
}

__global__ void __launch_bounds__(256)
moe_reduce(const float* __restrict__ blocksums, float* __restrict__ out)
{
    __shared__ float wavered[4];
    float v = 0.f;
    for (int i = threadIdx.x; i < BLOCKS; i += 256) v += blocksums[i];
    #pragma unroll
    for (int off = 32; off > 0; off >>= 1)
        v += __shfl_down(v, off);
    if ((threadIdx.x & 63) == 0) wavered[threadIdx.x >> 6] = v;
    __syncthreads();
    if (threadIdx.x == 0)
        out[0] = wavered[0] + wavered[1] + wavered[2] + wavered[3];
}

extern "C" void kernel_launch(void* const* d_in, const int* in_sizes, int n_in,
                              void* d_out, int out_size, void* d_ws, size_t ws_size,
                              hipStream_t stream)
{
    const float* inp = (const float*)d_in[0];
    const float* Wa  = (const float*)d_in[1];
    const float* ba  = (const float*)d_in[2];
    const float* Wb  = (const float*)d_in[3];
    const float* bb  = (const float*)d_in[4];
    const float* Wg  = (const float*)d_in[5];
    const float* bg  = (const float*)d_in[6];
    const float* We1 = (const float*)d_in[7];
    const float* be1 = (const float*)d_in[8];
    const float* We2 = (const float*)d_in[9];
    const float* be2 = (const float*)d_in[10];

    const int ntok = in_sizes[0] / 8;

    float* wsc       = (float*)d_ws;        // 640 floats of folded weights
    float* blocksums = (float*)d_ws + 640;  // BLOCKS floats
    float* out       = (float*)d_out;

    hipLaunchKernelGGL(moe_prep, dim3(1), dim3(640), 0, stream,
                       Wb, bb, Wg, bg, We1, be1, We2, be2, wsc);
    hipLaunchKernelGGL(moe_main, dim3(BLOCKS), dim3(THREADS), 0, stream,
                       inp, Wa, ba, wsc, blocksums, ntok);
    hipLaunchKernelGGL(moe_reduce, dim3(1), dim3(256), 0, stream,
                       blocksums, out);
}